// Round 1
// baseline (2205.968 us; speedup 1.0000x reference)
//
#include <hip/hip_runtime.h>

#define NN 50000
#define NE 800000
#define DD 64

// ---- one-time degree count + reciprocal ----
__global__ __launch_bounds__(256) void k_count(const int* __restrict__ dst, int* __restrict__ cnt) {
    int e = blockIdx.x * 256 + threadIdx.x;
    if (e < NE) atomicAdd(&cnt[dst[e]], 1);
}

__global__ __launch_bounds__(256) void k_inv(const int* __restrict__ cnt, float* __restrict__ inv) {
    int i = blockIdx.x * 256 + threadIdx.x;
    if (i < NN) inv[i] = 1.0f / (float)(cnt[i] > 1 ? cnt[i] : 1);
}

// ---- scatter-add of h[src] into agg[dst]; 16 threads per edge, float4 each ----
__global__ __launch_bounds__(256) void k_scatter(const float* __restrict__ h,
                                                 const int* __restrict__ src,
                                                 const int* __restrict__ dst,
                                                 float* __restrict__ agg) {
    long long gid = (long long)blockIdx.x * 256 + threadIdx.x;
    int e = (int)(gid >> 4);
    if (e >= NE) return;
    int c = ((int)gid & 15) * 4;
    int s = src[e], d = dst[e];
    float4 v = *(const float4*)(h + (long long)s * DD + c);
    float* o = agg + (long long)d * DD + c;
    atomicAdd(o + 0, v.x);
    atomicAdd(o + 1, v.y);
    atomicAdd(o + 2, v.z);
    atomicAdd(o + 3, v.w);
}

// ---- fused: out[i] = (agg[i]*inv[i]) @ Wl^T + bl + h[i] @ Wr^T, optional ReLU ----
// 64 rows per block, 256 threads: thread t -> row t&63, output cols [(t>>6)*16, +16)
__global__ __launch_bounds__(256) void k_gemm(const float* __restrict__ h,
                                              const float* __restrict__ agg,
                                              const float* __restrict__ inv,
                                              const float* __restrict__ Wl,
                                              const float* __restrict__ bl,
                                              const float* __restrict__ Wr,
                                              float* __restrict__ out,
                                              int relu)
{
    __shared__ float WlT[DD * DD];     // WlT[k*64 + j] = Wl[j*64 + k]
    __shared__ float WrT[DD * DD];
    __shared__ float xt[64 * 65];      // pad 65: banks (r+k)%32 -> 2-way only
    __shared__ float at[64 * 65];
    int t = threadIdx.x;
    int r0 = blockIdx.x * 64;

    // stage W transposed (16 elems / thread, float4 global loads)
    for (int i = t; i < DD * DD / 4; i += 256) {
        float4 a = ((const float4*)Wl)[i];
        float4 b = ((const float4*)Wr)[i];
        int flat = i * 4;
        int j = flat >> 6, k = flat & 63;
        WlT[(k + 0) * DD + j] = a.x; WlT[(k + 1) * DD + j] = a.y;
        WlT[(k + 2) * DD + j] = a.z; WlT[(k + 3) * DD + j] = a.w;
        WrT[(k + 0) * DD + j] = b.x; WrT[(k + 1) * DD + j] = b.y;
        WrT[(k + 2) * DD + j] = b.z; WrT[(k + 3) * DD + j] = b.w;
    }
    // stage x / agg tiles (agg scaled by 1/deg on load)
    for (int i = t; i < 64 * DD / 4; i += 256) {
        int flat = i * 4;
        int r = flat >> 6, c = flat & 63;
        int row = r0 + r;
        float4 xv = make_float4(0.f, 0.f, 0.f, 0.f), av = xv;
        if (row < NN) {
            xv = *(const float4*)(h + (long long)row * DD + c);
            av = *(const float4*)(agg + (long long)row * DD + c);
            float s = inv[row];
            av.x *= s; av.y *= s; av.z *= s; av.w *= s;
        }
        float* xp = &xt[r * 65 + c];
        xp[0] = xv.x; xp[1] = xv.y; xp[2] = xv.z; xp[3] = xv.w;
        float* ap = &at[r * 65 + c];
        ap[0] = av.x; ap[1] = av.y; ap[2] = av.z; ap[3] = av.w;
    }
    __syncthreads();

    int row = t & 63;
    int j0 = (t >> 6) * 16;
    float acc[16];
    #pragma unroll
    for (int q = 0; q < 16; q++) acc[q] = bl[j0 + q];

    #pragma unroll 4
    for (int k = 0; k < DD; k++) {
        float a = at[row * 65 + k];
        float x = xt[row * 65 + k];
        const float4* wl = (const float4*)&WlT[k * DD + j0];  // broadcast reads
        const float4* wr = (const float4*)&WrT[k * DD + j0];
        #pragma unroll
        for (int q = 0; q < 4; q++) {
            float4 wlv = wl[q];
            float4 wrv = wr[q];
            acc[q * 4 + 0] += a * wlv.x + x * wrv.x;
            acc[q * 4 + 1] += a * wlv.y + x * wrv.y;
            acc[q * 4 + 2] += a * wlv.z + x * wrv.z;
            acc[q * 4 + 3] += a * wlv.w + x * wrv.w;
        }
    }

    int grow = r0 + row;
    if (grow < NN) {
        float4* o = (float4*)(out + (long long)grow * DD + j0);
        #pragma unroll
        for (int q = 0; q < 4; q++) {
            float4 v = make_float4(acc[q * 4 + 0], acc[q * 4 + 1], acc[q * 4 + 2], acc[q * 4 + 3]);
            if (relu) {
                v.x = fmaxf(v.x, 0.f); v.y = fmaxf(v.y, 0.f);
                v.z = fmaxf(v.z, 0.f); v.w = fmaxf(v.w, 0.f);
            }
            o[q] = v;
        }
    }
}

extern "C" void kernel_launch(void* const* d_in, const int* in_sizes, int n_in,
                              void* d_out, int out_size, void* d_ws, size_t ws_size,
                              hipStream_t stream) {
    const float* x   = (const float*)d_in[0];
    const int*   ei  = (const int*)d_in[1];
    const int*   src = ei;            // edge_index[0]
    const int*   dst = ei + NE;       // edge_index[1]
    const float* Wl0 = (const float*)d_in[2];
    const float* bl0 = (const float*)d_in[3];
    const float* Wr0 = (const float*)d_in[4];
    const float* Wl1 = (const float*)d_in[5];
    const float* bl1 = (const float*)d_in[6];
    const float* Wr1 = (const float*)d_in[7];
    const float* Wl2 = (const float*)d_in[8];
    const float* bl2 = (const float*)d_in[9];
    const float* Wr2 = (const float*)d_in[10];
    float* out = (float*)d_out;

    char* ws = (char*)d_ws;
    float* agg = (float*)ws;                                   // NN*DD f32 = 12.8 MB
    float* h1  = (float*)(ws + (size_t)NN * DD * 4);           // NN*DD f32 = 12.8 MB
    float* inv = (float*)(ws + (size_t)NN * DD * 8);           // NN f32
    int*   cnt = (int*)  (ws + (size_t)NN * DD * 8 + (size_t)NN * 4);  // NN i32

    // degree (dst is layer-invariant) — once
    hipMemsetAsync(cnt, 0, (size_t)NN * sizeof(int), stream);
    k_count<<<(NE + 255) / 256, 256, 0, stream>>>(dst, cnt);
    k_inv<<<(NN + 255) / 256, 256, 0, stream>>>(cnt, inv);

    const int sg = (int)(((long long)NE * 16 + 255) / 256);
    const int gg = (NN + 63) / 64;

    // layer 0: x -> h1 (ReLU)
    hipMemsetAsync(agg, 0, (size_t)NN * DD * 4, stream);
    k_scatter<<<sg, 256, 0, stream>>>(x, src, dst, agg);
    k_gemm<<<gg, 256, 0, stream>>>(x, agg, inv, Wl0, bl0, Wr0, h1, 1);

    // layer 1: h1 -> out (ReLU)
    hipMemsetAsync(agg, 0, (size_t)NN * DD * 4, stream);
    k_scatter<<<sg, 256, 0, stream>>>(h1, src, dst, agg);
    k_gemm<<<gg, 256, 0, stream>>>(h1, agg, inv, Wl1, bl1, Wr1, out, 1);

    // layer 2: out -> out in-place (rows staged to LDS before writeback; no ReLU)
    hipMemsetAsync(agg, 0, (size_t)NN * DD * 4, stream);
    k_scatter<<<sg, 256, 0, stream>>>(out, src, dst, agg);
    k_gemm<<<gg, 256, 0, stream>>>(out, agg, inv, Wl2, bl2, Wr2, out, 0);
}

// Round 2
// 302.031 us; speedup vs baseline: 7.3038x; 7.3038x over previous
//
#include <hip/hip_runtime.h>

#define NN 50000
#define NE 800000
#define DD 64
#define NBLK 196   // ceil(NN/256)

// ---- one-time degree count ----
__global__ __launch_bounds__(256) void k_count(const int* __restrict__ dst, int* __restrict__ cnt) {
    int e = blockIdx.x * 256 + threadIdx.x;
    if (e < NE) atomicAdd(&cnt[dst[e]], 1);
}

__global__ __launch_bounds__(256) void k_inv(const int* __restrict__ cnt, float* __restrict__ inv) {
    int i = blockIdx.x * 256 + threadIdx.x;
    if (i < NN) inv[i] = 1.0f / (float)(cnt[i] > 1 ? cnt[i] : 1);
}

// ---- 3-phase exclusive scan of cnt -> offs ----
__global__ __launch_bounds__(256) void k_scan1(const int* __restrict__ cnt,
                                               int* __restrict__ incl, int* __restrict__ bsum) {
    __shared__ int sm[256];
    int t = threadIdx.x, i = blockIdx.x * 256 + t;
    int v = (i < NN) ? cnt[i] : 0;
    int acc = v;
    sm[t] = v; __syncthreads();
    #pragma unroll
    for (int off = 1; off < 256; off <<= 1) {
        int add = (t >= off) ? sm[t - off] : 0;
        __syncthreads();
        acc += add; sm[t] = acc;
        __syncthreads();
    }
    if (i < NN) incl[i] = acc;
    if (t == 255) bsum[blockIdx.x] = acc;
}

__global__ __launch_bounds__(256) void k_scan2(int* __restrict__ bsum, int* __restrict__ boff) {
    __shared__ int sm[256];
    int t = threadIdx.x;
    int v = (t < NBLK) ? bsum[t] : 0;
    int acc = v;
    sm[t] = v; __syncthreads();
    #pragma unroll
    for (int off = 1; off < 256; off <<= 1) {
        int add = (t >= off) ? sm[t - off] : 0;
        __syncthreads();
        acc += add; sm[t] = acc;
        __syncthreads();
    }
    boff[t] = acc - v;   // exclusive
}

__global__ __launch_bounds__(256) void k_scan3(const int* __restrict__ cnt, const int* __restrict__ incl,
                                               const int* __restrict__ boff,
                                               int* __restrict__ offs, int* __restrict__ cursor) {
    int i = blockIdx.x * 256 + threadIdx.x;
    if (i < NN) {
        int o = boff[i >> 8] + incl[i] - cnt[i];  // exclusive
        offs[i] = o;
        cursor[i] = o;
    }
    if (i == 0) offs[NN] = NE;
}

// ---- CSR fill (order within a node arbitrary; fp-add reorder << threshold) ----
__global__ __launch_bounds__(256) void k_fill(const int* __restrict__ src, const int* __restrict__ dst,
                                              int* __restrict__ cursor, int* __restrict__ csr) {
    int e = blockIdx.x * 256 + threadIdx.x;
    if (e < NE) {
        int p = atomicAdd(&cursor[dst[e]], 1);
        csr[p] = src[e];
    }
}

// ---- gather-aggregate: one wave per node, lane = column; mean applied here ----
__global__ __launch_bounds__(256) void k_aggregate(const float* __restrict__ h,
                                                   const int* __restrict__ offs,
                                                   const int* __restrict__ csr,
                                                   const float* __restrict__ inv,
                                                   float* __restrict__ agg) {
    int node = blockIdx.x * 4 + (threadIdx.x >> 6);
    if (node >= NN) return;
    int l = threadIdx.x & 63;
    int e0 = offs[node], e1 = offs[node + 1];
    float s = 0.f;
    for (int base = e0; base < e1; base += 64) {
        int nbr = (base + l < e1) ? csr[base + l] : 0;
        int m = e1 - base; if (m > 64) m = 64;
        int j = 0;
        for (; j + 4 <= m; j += 4) {
            int b0 = __shfl(nbr, j + 0);
            int b1 = __shfl(nbr, j + 1);
            int b2 = __shfl(nbr, j + 2);
            int b3 = __shfl(nbr, j + 3);
            float v0 = h[(long long)b0 * DD + l];
            float v1 = h[(long long)b1 * DD + l];
            float v2 = h[(long long)b2 * DD + l];
            float v3 = h[(long long)b3 * DD + l];
            s += (v0 + v1) + (v2 + v3);
        }
        for (; j < m; j++) {
            int b = __shfl(nbr, j);
            s += h[(long long)b * DD + l];
        }
    }
    agg[(long long)node * DD + l] = s * inv[node];
}

// ---- fused: out[i] = agg[i] @ Wl^T + bl + h[i] @ Wr^T, optional ReLU ----
__global__ __launch_bounds__(256) void k_gemm(const float* __restrict__ h,
                                              const float* __restrict__ agg,
                                              const float* __restrict__ Wl,
                                              const float* __restrict__ bl,
                                              const float* __restrict__ Wr,
                                              float* __restrict__ out,
                                              int relu)
{
    __shared__ float WlT[DD * DD];     // WlT[k*64 + j] = Wl[j*64 + k]
    __shared__ float WrT[DD * DD];
    __shared__ float xt[64 * 65];      // pad 65: 2-way bank aliasing only (free)
    __shared__ float at[64 * 65];
    int t = threadIdx.x;
    int r0 = blockIdx.x * 64;

    for (int i = t; i < DD * DD / 4; i += 256) {
        float4 a = ((const float4*)Wl)[i];
        float4 b = ((const float4*)Wr)[i];
        int flat = i * 4;
        int j = flat >> 6, k = flat & 63;
        WlT[(k + 0) * DD + j] = a.x; WlT[(k + 1) * DD + j] = a.y;
        WlT[(k + 2) * DD + j] = a.z; WlT[(k + 3) * DD + j] = a.w;
        WrT[(k + 0) * DD + j] = b.x; WrT[(k + 1) * DD + j] = b.y;
        WrT[(k + 2) * DD + j] = b.z; WrT[(k + 3) * DD + j] = b.w;
    }
    for (int i = t; i < 64 * DD / 4; i += 256) {
        int flat = i * 4;
        int r = flat >> 6, c = flat & 63;
        int row = r0 + r;
        float4 xv = make_float4(0.f, 0.f, 0.f, 0.f), av = xv;
        if (row < NN) {
            xv = *(const float4*)(h + (long long)row * DD + c);
            av = *(const float4*)(agg + (long long)row * DD + c);
        }
        float* xp = &xt[r * 65 + c];
        xp[0] = xv.x; xp[1] = xv.y; xp[2] = xv.z; xp[3] = xv.w;
        float* ap = &at[r * 65 + c];
        ap[0] = av.x; ap[1] = av.y; ap[2] = av.z; ap[3] = av.w;
    }
    __syncthreads();

    int row = t & 63;
    int j0 = (t >> 6) * 16;
    float acc[16];
    #pragma unroll
    for (int q = 0; q < 16; q++) acc[q] = bl[j0 + q];

    #pragma unroll 4
    for (int k = 0; k < DD; k++) {
        float a = at[row * 65 + k];
        float x = xt[row * 65 + k];
        const float4* wl = (const float4*)&WlT[k * DD + j0];
        const float4* wr = (const float4*)&WrT[k * DD + j0];
        #pragma unroll
        for (int q = 0; q < 4; q++) {
            float4 wlv = wl[q];
            float4 wrv = wr[q];
            acc[q * 4 + 0] += a * wlv.x + x * wrv.x;
            acc[q * 4 + 1] += a * wlv.y + x * wrv.y;
            acc[q * 4 + 2] += a * wlv.z + x * wrv.z;
            acc[q * 4 + 3] += a * wlv.w + x * wrv.w;
        }
    }

    int grow = r0 + row;
    if (grow < NN) {
        float4* o = (float4*)(out + (long long)grow * DD + j0);
        #pragma unroll
        for (int q = 0; q < 4; q++) {
            float4 v = make_float4(acc[q * 4 + 0], acc[q * 4 + 1], acc[q * 4 + 2], acc[q * 4 + 3]);
            if (relu) {
                v.x = fmaxf(v.x, 0.f); v.y = fmaxf(v.y, 0.f);
                v.z = fmaxf(v.z, 0.f); v.w = fmaxf(v.w, 0.f);
            }
            o[q] = v;
        }
    }
}

extern "C" void kernel_launch(void* const* d_in, const int* in_sizes, int n_in,
                              void* d_out, int out_size, void* d_ws, size_t ws_size,
                              hipStream_t stream) {
    const float* x   = (const float*)d_in[0];
    const int*   ei  = (const int*)d_in[1];
    const int*   src = ei;            // edge_index[0]
    const int*   dst = ei + NE;       // edge_index[1]
    const float* Wl0 = (const float*)d_in[2];
    const float* bl0 = (const float*)d_in[3];
    const float* Wr0 = (const float*)d_in[4];
    const float* Wl1 = (const float*)d_in[5];
    const float* bl1 = (const float*)d_in[6];
    const float* Wr1 = (const float*)d_in[7];
    const float* Wl2 = (const float*)d_in[8];
    const float* bl2 = (const float*)d_in[9];
    const float* Wr2 = (const float*)d_in[10];
    float* out = (float*)d_out;

    char* ws = (char*)d_ws;
    size_t o = 0;
    float* agg    = (float*)(ws + o); o += (size_t)NN * DD * 4;      // 12.8 MB
    float* h1     = (float*)(ws + o); o += (size_t)NN * DD * 4;      // 12.8 MB
    int*   offs   = (int*)  (ws + o); o += (size_t)(NN + 1) * 4;
    int*   cursor = (int*)  (ws + o); o += (size_t)NN * 4;
    int*   csr    = (int*)  (ws + o); o += (size_t)NE * 4;           // 3.2 MB
    float* inv    = (float*)(ws + o); o += (size_t)NN * 4;
    int*   cnt    = (int*)  (ws + o); o += (size_t)NN * 4;
    // scan temporaries aliased into agg's space (only used before first aggregate)
    int*   incl   = (int*)agg;
    int*   bsum   = (int*)(agg + NN);
    int*   boff   = (int*)(agg + NN + 256);

    // ---- CSR build (dst layer-invariant) ----
    hipMemsetAsync(cnt, 0, (size_t)NN * sizeof(int), stream);
    k_count<<<(NE + 255) / 256, 256, 0, stream>>>(dst, cnt);
    k_inv  <<<NBLK, 256, 0, stream>>>(cnt, inv);
    k_scan1<<<NBLK, 256, 0, stream>>>(cnt, incl, bsum);
    k_scan2<<<1,    256, 0, stream>>>(bsum, boff);
    k_scan3<<<NBLK, 256, 0, stream>>>(cnt, incl, boff, offs, cursor);
    k_fill <<<(NE + 255) / 256, 256, 0, stream>>>(src, dst, cursor, csr);

    const int ag = (NN + 3) / 4;     // 4 waves (nodes) per block
    const int gg = (NN + 63) / 64;

    // layer 0: x -> h1 (ReLU)
    k_aggregate<<<ag, 256, 0, stream>>>(x, offs, csr, inv, agg);
    k_gemm<<<gg, 256, 0, stream>>>(x, agg, Wl0, bl0, Wr0, h1, 1);

    // layer 1: h1 -> out (ReLU)
    k_aggregate<<<ag, 256, 0, stream>>>(h1, offs, csr, inv, agg);
    k_gemm<<<gg, 256, 0, stream>>>(h1, agg, Wl1, bl1, Wr1, out, 1);

    // layer 2: out -> out (no ReLU; rows staged to LDS before writeback)
    k_aggregate<<<ag, 256, 0, stream>>>(out, offs, csr, inv, agg);
    k_gemm<<<gg, 256, 0, stream>>>(out, agg, Wl2, bl2, Wr2, out, 0);
}

// Round 3
// 239.360 us; speedup vs baseline: 9.2161x; 1.2618x over previous
//
#include <hip/hip_runtime.h>

#define NN 50000
#define NE 800000
#define DD 64
#define BCAP 64        // bucket capacity per node (Poisson(16): P(>64) ~ 1e-19)
#define OVCAP 4096     // overflow list capacity

// ---- single-pass bucket fill: cursor ends as degree count ----
// 4 edges per thread, independent atomic->store chains for MLP
__global__ __launch_bounds__(256) void k_fillb(const int* __restrict__ src,
                                               const int* __restrict__ dst,
                                               int* __restrict__ cursor,
                                               unsigned short* __restrict__ bucket,
                                               int* __restrict__ ovn,
                                               int2* __restrict__ ov) {
    const int NT = gridDim.x * 256;
    int e0 = blockIdx.x * 256 + threadIdx.x;
    int e1 = e0 + NT, e2 = e1 + NT, e3 = e2 + NT;
    int s0 = 0, d0 = 0, s1 = 0, d1 = 0, s2 = 0, d2 = 0, s3 = 0, d3 = 0;
    bool v0 = e0 < NE, v1 = e1 < NE, v2 = e2 < NE, v3 = e3 < NE;
    if (v0) { s0 = src[e0]; d0 = dst[e0]; }
    if (v1) { s1 = src[e1]; d1 = dst[e1]; }
    if (v2) { s2 = src[e2]; d2 = dst[e2]; }
    if (v3) { s3 = src[e3]; d3 = dst[e3]; }
    int p0 = 0, p1 = 0, p2 = 0, p3 = 0;
    if (v0) p0 = atomicAdd(&cursor[d0], 1);
    if (v1) p1 = atomicAdd(&cursor[d1], 1);
    if (v2) p2 = atomicAdd(&cursor[d2], 1);
    if (v3) p3 = atomicAdd(&cursor[d3], 1);
    if (v0) { if (p0 < BCAP) bucket[d0 * BCAP + p0] = (unsigned short)s0;
              else { int q = atomicAdd(ovn, 1); if (q < OVCAP) ov[q] = make_int2(d0, s0); } }
    if (v1) { if (p1 < BCAP) bucket[d1 * BCAP + p1] = (unsigned short)s1;
              else { int q = atomicAdd(ovn, 1); if (q < OVCAP) ov[q] = make_int2(d1, s1); } }
    if (v2) { if (p2 < BCAP) bucket[d2 * BCAP + p2] = (unsigned short)s2;
              else { int q = atomicAdd(ovn, 1); if (q < OVCAP) ov[q] = make_int2(d2, s2); } }
    if (v3) { if (p3 < BCAP) bucket[d3 * BCAP + p3] = (unsigned short)s3;
              else { int q = atomicAdd(ovn, 1); if (q < OVCAP) ov[q] = make_int2(d3, s3); } }
}

// ---- gather-aggregate: one wave per node; 4 neighbors at a time via
//      16-lane x float4 groups; x2 unroll -> 8 row-loads in flight ----
__global__ __launch_bounds__(256) void k_aggregate(const float* __restrict__ h,
                                                   const int* __restrict__ cursor,
                                                   const unsigned short* __restrict__ bucket,
                                                   const int* __restrict__ ovn,
                                                   const int2* __restrict__ ov,
                                                   float* __restrict__ agg) {
    int node = blockIdx.x * 4 + (threadIdx.x >> 6);
    if (node >= NN) return;
    int l = threadIdx.x & 63;
    int sub = l >> 4;          // neighbor sub-group 0..3
    int cl = l & 15;           // float4 column block 0..15
    int deg = cursor[node];
    int kk = deg < BCAP ? deg : BCAP;
    int myid = (l < kk) ? (int)bucket[node * BCAP + l] : 0;

    float4 a0 = make_float4(0.f, 0.f, 0.f, 0.f);
    float4 a1 = make_float4(0.f, 0.f, 0.f, 0.f);
    for (int j = 0; j < kk; j += 8) {
        int i0 = j + sub, i1 = j + 4 + sub;
        int b0 = __shfl(myid, i0);
        int b1 = __shfl(myid, i1);
        float4 u0 = *(const float4*)(h + (size_t)b0 * DD + cl * 4);
        float4 u1 = *(const float4*)(h + (size_t)b1 * DD + cl * 4);
        if (i0 < kk) { a0.x += u0.x; a0.y += u0.y; a0.z += u0.z; a0.w += u0.w; }
        if (i1 < kk) { a1.x += u1.x; a1.y += u1.y; a1.z += u1.z; a1.w += u1.w; }
    }
    a0.x += a1.x; a0.y += a1.y; a0.z += a1.z; a0.w += a1.w;

    // overflow contributions (ovn==0 in practice -> one uniform scalar check)
    int nov = *ovn;
    if (nov > 0 && sub == 0) {
        if (nov > OVCAP) nov = OVCAP;
        for (int i = 0; i < nov; i++) {
            int2 p = ov[i];
            if (p.x == node) {
                float4 u = *(const float4*)(h + (size_t)p.y * DD + cl * 4);
                a0.x += u.x; a0.y += u.y; a0.z += u.z; a0.w += u.w;
            }
        }
    }

    // butterfly across the 4 sub-groups (xor 16, 32)
    a0.x += __shfl_xor(a0.x, 16); a0.y += __shfl_xor(a0.y, 16);
    a0.z += __shfl_xor(a0.z, 16); a0.w += __shfl_xor(a0.w, 16);
    a0.x += __shfl_xor(a0.x, 32); a0.y += __shfl_xor(a0.y, 32);
    a0.z += __shfl_xor(a0.z, 32); a0.w += __shfl_xor(a0.w, 32);

    if (sub == 0) {
        float inv = 1.0f / (float)(deg > 1 ? deg : 1);
        float4 r = make_float4(a0.x * inv, a0.y * inv, a0.z * inv, a0.w * inv);
        *(float4*)(agg + (size_t)node * DD + cl * 4) = r;
    }
}

// ---- fused: out[i] = agg[i] @ Wl^T + bl + h[i] @ Wr^T, optional ReLU ----
__global__ __launch_bounds__(256) void k_gemm(const float* __restrict__ h,
                                              const float* __restrict__ agg,
                                              const float* __restrict__ Wl,
                                              const float* __restrict__ bl,
                                              const float* __restrict__ Wr,
                                              float* __restrict__ out,
                                              int relu)
{
    __shared__ float WlT[DD * DD];
    __shared__ float WrT[DD * DD];
    __shared__ float xt[64 * 65];
    __shared__ float at[64 * 65];
    int t = threadIdx.x;
    int r0 = blockIdx.x * 64;

    for (int i = t; i < DD * DD / 4; i += 256) {
        float4 a = ((const float4*)Wl)[i];
        float4 b = ((const float4*)Wr)[i];
        int flat = i * 4;
        int j = flat >> 6, k = flat & 63;
        WlT[(k + 0) * DD + j] = a.x; WlT[(k + 1) * DD + j] = a.y;
        WlT[(k + 2) * DD + j] = a.z; WlT[(k + 3) * DD + j] = a.w;
        WrT[(k + 0) * DD + j] = b.x; WrT[(k + 1) * DD + j] = b.y;
        WrT[(k + 2) * DD + j] = b.z; WrT[(k + 3) * DD + j] = b.w;
    }
    for (int i = t; i < 64 * DD / 4; i += 256) {
        int flat = i * 4;
        int r = flat >> 6, c = flat & 63;
        int row = r0 + r;
        float4 xv = make_float4(0.f, 0.f, 0.f, 0.f), av = xv;
        if (row < NN) {
            xv = *(const float4*)(h + (size_t)row * DD + c);
            av = *(const float4*)(agg + (size_t)row * DD + c);
        }
        float* xp = &xt[r * 65 + c];
        xp[0] = xv.x; xp[1] = xv.y; xp[2] = xv.z; xp[3] = xv.w;
        float* ap = &at[r * 65 + c];
        ap[0] = av.x; ap[1] = av.y; ap[2] = av.z; ap[3] = av.w;
    }
    __syncthreads();

    int row = t & 63;
    int j0 = (t >> 6) * 16;
    float acc[16];
    #pragma unroll
    for (int q = 0; q < 16; q++) acc[q] = bl[j0 + q];

    #pragma unroll 4
    for (int k = 0; k < DD; k++) {
        float a = at[row * 65 + k];
        float x = xt[row * 65 + k];
        const float4* wl = (const float4*)&WlT[k * DD + j0];
        const float4* wr = (const float4*)&WrT[k * DD + j0];
        #pragma unroll
        for (int q = 0; q < 4; q++) {
            float4 wlv = wl[q];
            float4 wrv = wr[q];
            acc[q * 4 + 0] += a * wlv.x + x * wrv.x;
            acc[q * 4 + 1] += a * wlv.y + x * wrv.y;
            acc[q * 4 + 2] += a * wlv.z + x * wrv.z;
            acc[q * 4 + 3] += a * wlv.w + x * wrv.w;
        }
    }

    int grow = r0 + row;
    if (grow < NN) {
        float4* o = (float4*)(out + (size_t)grow * DD + j0);
        #pragma unroll
        for (int q = 0; q < 4; q++) {
            float4 v = make_float4(acc[q * 4 + 0], acc[q * 4 + 1], acc[q * 4 + 2], acc[q * 4 + 3]);
            if (relu) {
                v.x = fmaxf(v.x, 0.f); v.y = fmaxf(v.y, 0.f);
                v.z = fmaxf(v.z, 0.f); v.w = fmaxf(v.w, 0.f);
            }
            o[q] = v;
        }
    }
}

extern "C" void kernel_launch(void* const* d_in, const int* in_sizes, int n_in,
                              void* d_out, int out_size, void* d_ws, size_t ws_size,
                              hipStream_t stream) {
    const float* x   = (const float*)d_in[0];
    const int*   ei  = (const int*)d_in[1];
    const int*   src = ei;            // edge_index[0]
    const int*   dst = ei + NE;       // edge_index[1]
    const float* Wl0 = (const float*)d_in[2];
    const float* bl0 = (const float*)d_in[3];
    const float* Wr0 = (const float*)d_in[4];
    const float* Wl1 = (const float*)d_in[5];
    const float* bl1 = (const float*)d_in[6];
    const float* Wr1 = (const float*)d_in[7];
    const float* Wl2 = (const float*)d_in[8];
    const float* bl2 = (const float*)d_in[9];
    const float* Wr2 = (const float*)d_in[10];
    float* out = (float*)d_out;

    char* ws = (char*)d_ws;
    size_t o = 0;
    float*          agg    = (float*)(ws + o);          o += (size_t)NN * DD * 4;     // 12.8 MB
    float*          h1     = (float*)(ws + o);          o += (size_t)NN * DD * 4;     // 12.8 MB
    unsigned short* bucket = (unsigned short*)(ws + o); o += (size_t)NN * BCAP * 2;   // 6.4 MB
    int*            cursor = (int*)(ws + o);            o += (size_t)NN * 4;          // 200 KB
    int*            ovn    = (int*)(ws + o);            o += 16;
    int2*           ov     = (int2*)(ws + o);           o += (size_t)OVCAP * 8;       // 32 KB

    // ---- bucket build (dst layer-invariant): one pass, cursor ends as degree ----
    hipMemsetAsync(cursor, 0, (size_t)NN * sizeof(int), stream);
    hipMemsetAsync(ovn, 0, sizeof(int), stream);
    const int fg = (NE + 256 * 4 - 1) / (256 * 4);
    k_fillb<<<fg, 256, 0, stream>>>(src, dst, cursor, bucket, ovn, ov);

    const int ag = (NN + 3) / 4;     // one wave per node, 4 per block
    const int gg = (NN + 63) / 64;

    // layer 0: x -> h1 (ReLU)
    k_aggregate<<<ag, 256, 0, stream>>>(x, cursor, bucket, ovn, ov, agg);
    k_gemm<<<gg, 256, 0, stream>>>(x, agg, Wl0, bl0, Wr0, h1, 1);

    // layer 1: h1 -> out (ReLU)
    k_aggregate<<<ag, 256, 0, stream>>>(h1, cursor, bucket, ovn, ov, agg);
    k_gemm<<<gg, 256, 0, stream>>>(h1, agg, Wl1, bl1, Wr1, out, 1);

    // layer 2: out -> out (no ReLU; gemm is row-local so in-place is safe)
    k_aggregate<<<ag, 256, 0, stream>>>(out, cursor, bucket, ovn, ov, agg);
    k_gemm<<<gg, 256, 0, stream>>>(out, agg, Wl2, bl2, Wr2, out, 0);
}

// Round 4
// 216.721 us; speedup vs baseline: 10.1788x; 1.1045x over previous
//
#include <hip/hip_runtime.h>
#include <hip/hip_fp16.h>

#define NN 50000
#define NE 800000
#define DD 64
#define BCAP 64        // bucket capacity per node (Poisson(16): P(>64) ~ 1e-19)
#define OVCAP 4096     // overflow list capacity

typedef unsigned short u16;
typedef unsigned int u32;

// ---- single-pass bucket fill: cursor ends as degree count ----
__global__ __launch_bounds__(256) void k_fillb(const int* __restrict__ src,
                                               const int* __restrict__ dst,
                                               int* __restrict__ cursor,
                                               u16* __restrict__ bucket,
                                               int* __restrict__ ovn,
                                               int2* __restrict__ ov) {
    const int NT = gridDim.x * 256;
    int e0 = blockIdx.x * 256 + threadIdx.x;
    int e1 = e0 + NT, e2 = e1 + NT, e3 = e2 + NT;
    int s0 = 0, d0 = 0, s1 = 0, d1 = 0, s2 = 0, d2 = 0, s3 = 0, d3 = 0;
    bool v0 = e0 < NE, v1 = e1 < NE, v2 = e2 < NE, v3 = e3 < NE;
    if (v0) { s0 = src[e0]; d0 = dst[e0]; }
    if (v1) { s1 = src[e1]; d1 = dst[e1]; }
    if (v2) { s2 = src[e2]; d2 = dst[e2]; }
    if (v3) { s3 = src[e3]; d3 = dst[e3]; }
    int p0 = 0, p1 = 0, p2 = 0, p3 = 0;
    if (v0) p0 = atomicAdd(&cursor[d0], 1);
    if (v1) p1 = atomicAdd(&cursor[d1], 1);
    if (v2) p2 = atomicAdd(&cursor[d2], 1);
    if (v3) p3 = atomicAdd(&cursor[d3], 1);
    if (v0) { if (p0 < BCAP) bucket[(size_t)d0 * BCAP + p0] = (u16)s0;
              else { int q = atomicAdd(ovn, 1); if (q < OVCAP) ov[q] = make_int2(d0, s0); } }
    if (v1) { if (p1 < BCAP) bucket[(size_t)d1 * BCAP + p1] = (u16)s1;
              else { int q = atomicAdd(ovn, 1); if (q < OVCAP) ov[q] = make_int2(d1, s1); } }
    if (v2) { if (p2 < BCAP) bucket[(size_t)d2 * BCAP + p2] = (u16)s2;
              else { int q = atomicAdd(ovn, 1); if (q < OVCAP) ov[q] = make_int2(d2, s2); } }
    if (v3) { if (p3 < BCAP) bucket[(size_t)d3 * BCAP + p3] = (u16)s3;
              else { int q = atomicAdd(ovn, 1); if (q < OVCAP) ov[q] = make_int2(d3, s3); } }
}

// ---- fp32 -> fp16 convert (one float4 per thread) ----
__global__ __launch_bounds__(256) void k_tohalf(const float* __restrict__ x, u16* __restrict__ xh) {
    int i = blockIdx.x * 256 + threadIdx.x;
    if (i >= NN * DD / 4) return;
    float4 v = ((const float4*)x)[i];
    __half2 h01 = __floats2half2_rn(v.x, v.y);
    __half2 h23 = __floats2half2_rn(v.z, v.w);
    uint2 pk;
    pk.x = *(u32*)&h01; pk.y = *(u32*)&h23;
    ((uint2*)xh)[i] = pk;
}

// ---- gather-aggregate from fp16 rows: one wave per node;
//      4 sub-groups x 16 lanes, each lane = 4 columns (8B loads);
//      16 neighbors in flight per iteration ----
__global__ __launch_bounds__(256) void k_aggregate(const u16* __restrict__ h16,
                                                   const int* __restrict__ cursor,
                                                   const u16* __restrict__ bucket,
                                                   const int* __restrict__ ovn,
                                                   const int2* __restrict__ ov,
                                                   float* __restrict__ agg) {
    int node = blockIdx.x * 4 + (threadIdx.x >> 6);
    int l = threadIdx.x & 63;
    int sub = l >> 4;          // neighbor sub-group 0..3
    int cl = l & 15;           // 4-col block 0..15
    int deg = cursor[node];
    int kk = deg < BCAP ? deg : BCAP;
    int myid = (l < kk) ? (int)bucket[(size_t)node * BCAP + l] : 0;

    float s0 = 0.f, s1 = 0.f, s2 = 0.f, s3 = 0.f;
    for (int j = 0; j < kk; j += 16) {
        int i0 = j + sub, i1 = j + 4 + sub, i2 = j + 8 + sub, i3 = j + 12 + sub;
        int b0 = __shfl(myid, i0);
        int b1 = __shfl(myid, i1);
        int b2 = __shfl(myid, i2);
        int b3 = __shfl(myid, i3);
        uint2 u0 = *(const uint2*)(h16 + (size_t)b0 * DD + cl * 4);
        uint2 u1 = *(const uint2*)(h16 + (size_t)b1 * DD + cl * 4);
        uint2 u2 = *(const uint2*)(h16 + (size_t)b2 * DD + cl * 4);
        uint2 u3 = *(const uint2*)(h16 + (size_t)b3 * DD + cl * 4);
        if (i0 < kk) { float2 f0 = __half22float2(*(__half2*)&u0.x), f1 = __half22float2(*(__half2*)&u0.y);
                       s0 += f0.x; s1 += f0.y; s2 += f1.x; s3 += f1.y; }
        if (i1 < kk) { float2 f0 = __half22float2(*(__half2*)&u1.x), f1 = __half22float2(*(__half2*)&u1.y);
                       s0 += f0.x; s1 += f0.y; s2 += f1.x; s3 += f1.y; }
        if (i2 < kk) { float2 f0 = __half22float2(*(__half2*)&u2.x), f1 = __half22float2(*(__half2*)&u2.y);
                       s0 += f0.x; s1 += f0.y; s2 += f1.x; s3 += f1.y; }
        if (i3 < kk) { float2 f0 = __half22float2(*(__half2*)&u3.x), f1 = __half22float2(*(__half2*)&u3.y);
                       s0 += f0.x; s1 += f0.y; s2 += f1.x; s3 += f1.y; }
    }

    // overflow contributions (ovn==0 in practice -> one uniform scalar check)
    int nov = *ovn;
    if (nov > 0 && sub == 0) {
        if (nov > OVCAP) nov = OVCAP;
        for (int i = 0; i < nov; i++) {
            int2 p = ov[i];
            if (p.x == node) {
                uint2 u = *(const uint2*)(h16 + (size_t)p.y * DD + cl * 4);
                float2 f0 = __half22float2(*(__half2*)&u.x), f1 = __half22float2(*(__half2*)&u.y);
                s0 += f0.x; s1 += f0.y; s2 += f1.x; s3 += f1.y;
            }
        }
    }

    // butterfly across the 4 sub-groups
    s0 += __shfl_xor(s0, 16); s1 += __shfl_xor(s1, 16);
    s2 += __shfl_xor(s2, 16); s3 += __shfl_xor(s3, 16);
    s0 += __shfl_xor(s0, 32); s1 += __shfl_xor(s1, 32);
    s2 += __shfl_xor(s2, 32); s3 += __shfl_xor(s3, 32);

    if (sub == 0) {
        float inv = 1.0f / (float)(deg > 1 ? deg : 1);
        float4 r = make_float4(s0 * inv, s1 * inv, s2 * inv, s3 * inv);
        *(float4*)(agg + (size_t)node * DD + cl * 4) = r;
    }
}

// ---- fused dense: out = agg @ Wl^T + bl + h @ Wr^T (+ReLU)
// W read via wave-uniform s_loads (scalar pipe) -> zero LDS for W.
// MODE 0: src fp32, out fp16, ReLU | MODE 1: src fp16, out fp16, ReLU
// MODE 2: src fp16, out fp32, no ReLU
template<int MODE>
__global__ __launch_bounds__(256) void k_gemm(const float* __restrict__ hsrc32,
                                              const u16* __restrict__ hsrc16,
                                              const float* __restrict__ agg,
                                              const float* __restrict__ Wl,
                                              const float* __restrict__ bl,
                                              const float* __restrict__ Wr,
                                              float* __restrict__ out32,
                                              u16* __restrict__ out16)
{
    __shared__ float xt[64 * 65];   // pad 65: 2-way bank aliasing only (free)
    __shared__ float at[64 * 65];
    int t = threadIdx.x;
    int r0 = blockIdx.x * 64;

    for (int i = t; i < 1024; i += 256) {     // 64 rows x 16 float4
        int r = i >> 4, c4 = i & 15;
        int row = r0 + r;
        float4 xv = make_float4(0.f, 0.f, 0.f, 0.f), av = xv;
        if (row < NN) {
            if (MODE == 0) {
                xv = *(const float4*)(hsrc32 + (size_t)row * DD + c4 * 4);
            } else {
                uint2 u = *(const uint2*)(hsrc16 + (size_t)row * DD + c4 * 4);
                float2 f0 = __half22float2(*(__half2*)&u.x);
                float2 f1 = __half22float2(*(__half2*)&u.y);
                xv = make_float4(f0.x, f0.y, f1.x, f1.y);
            }
            av = *(const float4*)(agg + (size_t)row * DD + c4 * 4);
        }
        float* xp = &xt[r * 65 + c4 * 4];
        xp[0] = xv.x; xp[1] = xv.y; xp[2] = xv.z; xp[3] = xv.w;
        float* ap = &at[r * 65 + c4 * 4];
        ap[0] = av.x; ap[1] = av.y; ap[2] = av.z; ap[3] = av.w;
    }
    __syncthreads();

    int row = t & 63;
    int j0 = __builtin_amdgcn_readfirstlane((t >> 6) * 16);   // wave-uniform SGPR
    float acc[16];
    #pragma unroll
    for (int q = 0; q < 16; q++) acc[q] = bl[j0 + q];         // uniform s_load

    #pragma unroll 4
    for (int k = 0; k < DD; k++) {
        float a = at[row * 65 + k];
        float x = xt[row * 65 + k];
        #pragma unroll
        for (int q = 0; q < 16; q++) {
            acc[q] = fmaf(a, Wl[(j0 + q) * DD + k], acc[q]);  // SGPR operand FMAs
            acc[q] = fmaf(x, Wr[(j0 + q) * DD + k], acc[q]);
        }
    }

    int grow = r0 + row;
    if (grow < NN) {
        if (MODE != 2) {
            #pragma unroll
            for (int q = 0; q < 16; q++) acc[q] = fmaxf(acc[q], 0.f);
            u32 w[8];
            #pragma unroll
            for (int p = 0; p < 8; p++) {
                __half2 hv = __floats2half2_rn(acc[2 * p], acc[2 * p + 1]);
                w[p] = *(u32*)&hv;
            }
            uint4* dst = (uint4*)(out16 + (size_t)grow * DD + j0);
            dst[0] = make_uint4(w[0], w[1], w[2], w[3]);
            dst[1] = make_uint4(w[4], w[5], w[6], w[7]);
        } else {
            float4* o = (float4*)(out32 + (size_t)grow * DD + j0);
            #pragma unroll
            for (int q4 = 0; q4 < 4; q4++)
                o[q4] = make_float4(acc[q4 * 4 + 0], acc[q4 * 4 + 1],
                                    acc[q4 * 4 + 2], acc[q4 * 4 + 3]);
        }
    }
}

extern "C" void kernel_launch(void* const* d_in, const int* in_sizes, int n_in,
                              void* d_out, int out_size, void* d_ws, size_t ws_size,
                              hipStream_t stream) {
    const float* x   = (const float*)d_in[0];
    const int*   ei  = (const int*)d_in[1];
    const int*   src = ei;            // edge_index[0]
    const int*   dst = ei + NE;       // edge_index[1]
    const float* Wl0 = (const float*)d_in[2];
    const float* bl0 = (const float*)d_in[3];
    const float* Wr0 = (const float*)d_in[4];
    const float* Wl1 = (const float*)d_in[5];
    const float* bl1 = (const float*)d_in[6];
    const float* Wr1 = (const float*)d_in[7];
    const float* Wl2 = (const float*)d_in[8];
    const float* bl2 = (const float*)d_in[9];
    const float* Wr2 = (const float*)d_in[10];
    float* out = (float*)d_out;

    char* ws = (char*)d_ws;
    size_t o = 0;
    float* agg    = (float*)(ws + o); o += (size_t)NN * DD * 4;   // 12.8 MB
    u16*   h16A   = (u16*)(ws + o);   o += (size_t)NN * DD * 2;   // 6.4 MB
    u16*   h16B   = (u16*)(ws + o);   o += (size_t)NN * DD * 2;   // 6.4 MB
    u16*   bucket = (u16*)(ws + o);   o += (size_t)NN * BCAP * 2; // 6.4 MB
    int*   cursor = (int*)(ws + o);   o += (size_t)NN * 4;        // 200 KB
    int*   ovn    = (int*)(ws + o);   o += 16;                    // adjacent to cursor
    int2*  ov     = (int2*)(ws + o);  o += (size_t)OVCAP * 8;     // 32 KB

    // ---- bucket build (dst layer-invariant): one pass, cursor ends as degree ----
    hipMemsetAsync(cursor, 0, (size_t)NN * 4 + 16, stream);       // cursor + ovn
    const int fg = (NE + 1023) / 1024;
    k_fillb<<<fg, 256, 0, stream>>>(src, dst, cursor, bucket, ovn, ov);
    k_tohalf<<<(NN * DD / 4 + 255) / 256, 256, 0, stream>>>(x, h16B);

    const int ag = NN / 4;           // one wave per node, 4 per block (50000 % 4 == 0)
    const int gg = (NN + 63) / 64;

    // layer 0: x -> h16A (ReLU)
    k_aggregate<<<ag, 256, 0, stream>>>(h16B, cursor, bucket, ovn, ov, agg);
    k_gemm<0><<<gg, 256, 0, stream>>>(x, nullptr, agg, Wl0, bl0, Wr0, nullptr, h16A);

    // layer 1: h16A -> h16B (ReLU)
    k_aggregate<<<ag, 256, 0, stream>>>(h16A, cursor, bucket, ovn, ov, agg);
    k_gemm<1><<<gg, 256, 0, stream>>>(nullptr, h16A, agg, Wl1, bl1, Wr1, nullptr, h16B);

    // layer 2: h16B -> out fp32 (no ReLU)
    k_aggregate<<<ag, 256, 0, stream>>>(h16B, cursor, bucket, ovn, ov, agg);
    k_gemm<2><<<gg, 256, 0, stream>>>(nullptr, h16B, agg, Wl2, bl2, Wr2, out, nullptr);
}

// Round 5
// 213.703 us; speedup vs baseline: 10.3226x; 1.0141x over previous
//
#include <hip/hip_runtime.h>
#include <hip/hip_fp16.h>

#define NN 50000
#define NE 800000
#define DD 64
#define BCAP 64        // bucket capacity per node (Poisson(16): P(>64) ~ 1e-19)
#define OVCAP 4096     // overflow list capacity
#define FG 782         // fill blocks: ceil(NE / (256*4))
#define CG 3125        // tohalf blocks: NN*DD/4 / 256

typedef unsigned short u16;
typedef unsigned int u32;

// ---- merged prep: bucket fill (atomic-bound) + x->fp16 convert (BW, overlaps) ----
__global__ __launch_bounds__(256) void k_prep(const int* __restrict__ src,
                                              const int* __restrict__ dst,
                                              int* __restrict__ cursor,
                                              u16* __restrict__ bucket,
                                              int* __restrict__ ovn,
                                              int2* __restrict__ ov,
                                              const float* __restrict__ x,
                                              u16* __restrict__ xh) {
    if (blockIdx.x >= FG) {
        int i = (blockIdx.x - FG) * 256 + threadIdx.x;
        if (i < NN * DD / 4) {
            float4 v = ((const float4*)x)[i];
            __half2 h01 = __floats2half2_rn(v.x, v.y);
            __half2 h23 = __floats2half2_rn(v.z, v.w);
            uint2 pk;
            pk.x = *(u32*)&h01; pk.y = *(u32*)&h23;
            ((uint2*)xh)[i] = pk;
        }
        return;
    }
    const int NT = FG * 256;
    int e0 = blockIdx.x * 256 + threadIdx.x;
    int e1 = e0 + NT, e2 = e1 + NT, e3 = e2 + NT;
    int s0 = 0, d0 = 0, s1 = 0, d1 = 0, s2 = 0, d2 = 0, s3 = 0, d3 = 0;
    bool v0 = e0 < NE, v1 = e1 < NE, v2 = e2 < NE, v3 = e3 < NE;
    if (v0) { s0 = src[e0]; d0 = dst[e0]; }
    if (v1) { s1 = src[e1]; d1 = dst[e1]; }
    if (v2) { s2 = src[e2]; d2 = dst[e2]; }
    if (v3) { s3 = src[e3]; d3 = dst[e3]; }
    int p0 = 0, p1 = 0, p2 = 0, p3 = 0;
    if (v0) p0 = atomicAdd(&cursor[d0], 1);
    if (v1) p1 = atomicAdd(&cursor[d1], 1);
    if (v2) p2 = atomicAdd(&cursor[d2], 1);
    if (v3) p3 = atomicAdd(&cursor[d3], 1);
    if (v0) { if (p0 < BCAP) bucket[(size_t)d0 * BCAP + p0] = (u16)s0;
              else { int q = atomicAdd(ovn, 1); if (q < OVCAP) ov[q] = make_int2(d0, s0); } }
    if (v1) { if (p1 < BCAP) bucket[(size_t)d1 * BCAP + p1] = (u16)s1;
              else { int q = atomicAdd(ovn, 1); if (q < OVCAP) ov[q] = make_int2(d1, s1); } }
    if (v2) { if (p2 < BCAP) bucket[(size_t)d2 * BCAP + p2] = (u16)s2;
              else { int q = atomicAdd(ovn, 1); if (q < OVCAP) ov[q] = make_int2(d2, s2); } }
    if (v3) { if (p3 < BCAP) bucket[(size_t)d3 * BCAP + p3] = (u16)s3;
              else { int q = atomicAdd(ovn, 1); if (q < OVCAP) ov[q] = make_int2(d3, s3); } }
}

// ---- fused layer: aggregate 64 nodes into LDS, then dense part from LDS ----
// LAST=0: fp16 out + ReLU | LAST=1: fp32 out, no ReLU
template<int LAST>
__global__ __launch_bounds__(256) void k_layer(const u16* __restrict__ h16,
                                               const int* __restrict__ cursor,
                                               const u16* __restrict__ bucket,
                                               const int* __restrict__ ovn,
                                               const int2* __restrict__ ov,
                                               const float* __restrict__ Wl,
                                               const float* __restrict__ bl,
                                               const float* __restrict__ Wr,
                                               u16* __restrict__ out16,
                                               float* __restrict__ out32)
{
    __shared__ float xt[64 * 65];   // pad 65: stride 65 -> conflict-free column reads
    __shared__ float at[64 * 65];
    int t = threadIdx.x;
    int r0 = blockIdx.x * 64;
    int wid = t >> 6, l = t & 63, sub = l >> 4, cl = l & 15;

    // ---- stage xt: block's own 64 rows (fp16 -> fp32) ----
    for (int i = t; i < 1024; i += 256) {    // 64 rows x 16 uint2
        int r = i >> 4, c4 = i & 15;
        int row = r0 + r;
        float4 xv = make_float4(0.f, 0.f, 0.f, 0.f);
        if (row < NN) {
            uint2 u = *(const uint2*)(h16 + (size_t)row * DD + c4 * 4);
            float2 f0 = __half22float2(*(__half2*)&u.x);
            float2 f1 = __half22float2(*(__half2*)&u.y);
            xv = make_float4(f0.x, f0.y, f1.x, f1.y);
        }
        float* xp = &xt[r * 65 + c4 * 4];
        xp[0] = xv.x; xp[1] = xv.y; xp[2] = xv.z; xp[3] = xv.w;
    }

    // ---- phase A: each wave aggregates 16 nodes, 2 concurrently (8 loads in flight/lane) ----
    for (int i = 0; i < 16; i += 2) {
        int rA = wid * 16 + i, rB = rA + 1;
        int nodeA = r0 + rA, nodeB = r0 + rB;
        bool vA = nodeA < NN, vB = nodeB < NN;
        int degA = vA ? cursor[nodeA] : 0;
        int degB = vB ? cursor[nodeB] : 0;
        int kkA = degA < BCAP ? degA : BCAP;
        int kkB = degB < BCAP ? degB : BCAP;
        int idA = (l < kkA) ? (int)bucket[(size_t)nodeA * BCAP + l] : 0;
        int idB = (l < kkB) ? (int)bucket[(size_t)nodeB * BCAP + l] : 0;
        float a0 = 0.f, a1 = 0.f, a2 = 0.f, a3 = 0.f;
        float b0 = 0.f, b1 = 0.f, b2 = 0.f, b3 = 0.f;
        int kmax = kkA > kkB ? kkA : kkB;
        for (int j = 0; j < kmax; j += 16) {
            int i0 = j + sub, i1 = j + 4 + sub, i2 = j + 8 + sub, i3 = j + 12 + sub;
            int nA0 = __shfl(idA, i0), nA1 = __shfl(idA, i1);
            int nA2 = __shfl(idA, i2), nA3 = __shfl(idA, i3);
            int nB0 = __shfl(idB, i0), nB1 = __shfl(idB, i1);
            int nB2 = __shfl(idB, i2), nB3 = __shfl(idB, i3);
            uint2 uA0 = *(const uint2*)(h16 + (size_t)nA0 * DD + cl * 4);
            uint2 uA1 = *(const uint2*)(h16 + (size_t)nA1 * DD + cl * 4);
            uint2 uA2 = *(const uint2*)(h16 + (size_t)nA2 * DD + cl * 4);
            uint2 uA3 = *(const uint2*)(h16 + (size_t)nA3 * DD + cl * 4);
            uint2 uB0 = *(const uint2*)(h16 + (size_t)nB0 * DD + cl * 4);
            uint2 uB1 = *(const uint2*)(h16 + (size_t)nB1 * DD + cl * 4);
            uint2 uB2 = *(const uint2*)(h16 + (size_t)nB2 * DD + cl * 4);
            uint2 uB3 = *(const uint2*)(h16 + (size_t)nB3 * DD + cl * 4);
            if (i0 < kkA) { float2 f0 = __half22float2(*(__half2*)&uA0.x), f1 = __half22float2(*(__half2*)&uA0.y);
                            a0 += f0.x; a1 += f0.y; a2 += f1.x; a3 += f1.y; }
            if (i1 < kkA) { float2 f0 = __half22float2(*(__half2*)&uA1.x), f1 = __half22float2(*(__half2*)&uA1.y);
                            a0 += f0.x; a1 += f0.y; a2 += f1.x; a3 += f1.y; }
            if (i2 < kkA) { float2 f0 = __half22float2(*(__half2*)&uA2.x), f1 = __half22float2(*(__half2*)&uA2.y);
                            a0 += f0.x; a1 += f0.y; a2 += f1.x; a3 += f1.y; }
            if (i3 < kkA) { float2 f0 = __half22float2(*(__half2*)&uA3.x), f1 = __half22float2(*(__half2*)&uA3.y);
                            a0 += f0.x; a1 += f0.y; a2 += f1.x; a3 += f1.y; }
            if (i0 < kkB) { float2 f0 = __half22float2(*(__half2*)&uB0.x), f1 = __half22float2(*(__half2*)&uB0.y);
                            b0 += f0.x; b1 += f0.y; b2 += f1.x; b3 += f1.y; }
            if (i1 < kkB) { float2 f0 = __half22float2(*(__half2*)&uB1.x), f1 = __half22float2(*(__half2*)&uB1.y);
                            b0 += f0.x; b1 += f0.y; b2 += f1.x; b3 += f1.y; }
            if (i2 < kkB) { float2 f0 = __half22float2(*(__half2*)&uB2.x), f1 = __half22float2(*(__half2*)&uB2.y);
                            b0 += f0.x; b1 += f0.y; b2 += f1.x; b3 += f1.y; }
            if (i3 < kkB) { float2 f0 = __half22float2(*(__half2*)&uB3.x), f1 = __half22float2(*(__half2*)&uB3.y);
                            b0 += f0.x; b1 += f0.y; b2 += f1.x; b3 += f1.y; }
        }

        // overflow contributions (empty in practice -> uniform scalar check)
        int nov = *ovn;
        if (nov > 0) {
            if (nov > OVCAP) nov = OVCAP;
            for (int q = 0; q < nov; q++) {
                int2 p = ov[q];
                bool mA = (sub == 0) && vA && (p.x == nodeA);
                bool mB = (sub == 1) && vB && (p.x == nodeB);
                if (mA | mB) {
                    uint2 u = *(const uint2*)(h16 + (size_t)p.y * DD + cl * 4);
                    float2 f0 = __half22float2(*(__half2*)&u.x), f1 = __half22float2(*(__half2*)&u.y);
                    if (mA) { a0 += f0.x; a1 += f0.y; a2 += f1.x; a3 += f1.y; }
                    else    { b0 += f0.x; b1 += f0.y; b2 += f1.x; b3 += f1.y; }
                }
            }
        }

        // butterfly across the 4 sub-groups
        a0 += __shfl_xor(a0, 16); a1 += __shfl_xor(a1, 16);
        a2 += __shfl_xor(a2, 16); a3 += __shfl_xor(a3, 16);
        a0 += __shfl_xor(a0, 32); a1 += __shfl_xor(a1, 32);
        a2 += __shfl_xor(a2, 32); a3 += __shfl_xor(a3, 32);
        b0 += __shfl_xor(b0, 16); b1 += __shfl_xor(b1, 16);
        b2 += __shfl_xor(b2, 16); b3 += __shfl_xor(b3, 16);
        b0 += __shfl_xor(b0, 32); b1 += __shfl_xor(b1, 32);
        b2 += __shfl_xor(b2, 32); b3 += __shfl_xor(b3, 32);

        if (sub == 0) {
            float invA = 1.0f / (float)(degA > 1 ? degA : 1);
            float* ap = &at[rA * 65 + cl * 4];
            ap[0] = a0 * invA; ap[1] = a1 * invA; ap[2] = a2 * invA; ap[3] = a3 * invA;
            float invB = 1.0f / (float)(degB > 1 ? degB : 1);
            float* bp = &at[rB * 65 + cl * 4];
            bp[0] = b0 * invB; bp[1] = b1 * invB; bp[2] = b2 * invB; bp[3] = b3 * invB;
        }
    }
    __syncthreads();

    // ---- phase B: out = at @ Wl^T + bl + xt @ Wr^T ; W via wave-uniform s_loads ----
    int row = l;
    int j0 = __builtin_amdgcn_readfirstlane(wid * 16);
    float acc[16];
    #pragma unroll
    for (int q = 0; q < 16; q++) acc[q] = bl[j0 + q];

    #pragma unroll 4
    for (int k = 0; k < DD; k++) {
        float a = at[row * 65 + k];
        float x = xt[row * 65 + k];
        #pragma unroll
        for (int q = 0; q < 16; q++) {
            acc[q] = fmaf(a, Wl[(j0 + q) * DD + k], acc[q]);
            acc[q] = fmaf(x, Wr[(j0 + q) * DD + k], acc[q]);
        }
    }

    int grow = r0 + row;
    if (grow < NN) {
        if (LAST == 0) {
            #pragma unroll
            for (int q = 0; q < 16; q++) acc[q] = fmaxf(acc[q], 0.f);
            u32 w[8];
            #pragma unroll
            for (int p = 0; p < 8; p++) {
                __half2 hv = __floats2half2_rn(acc[2 * p], acc[2 * p + 1]);
                w[p] = *(u32*)&hv;
            }
            uint4* dstp = (uint4*)(out16 + (size_t)grow * DD + j0);
            dstp[0] = make_uint4(w[0], w[1], w[2], w[3]);
            dstp[1] = make_uint4(w[4], w[5], w[6], w[7]);
        } else {
            float4* o = (float4*)(out32 + (size_t)grow * DD + j0);
            #pragma unroll
            for (int q4 = 0; q4 < 4; q4++)
                o[q4] = make_float4(acc[q4 * 4 + 0], acc[q4 * 4 + 1],
                                    acc[q4 * 4 + 2], acc[q4 * 4 + 3]);
        }
    }
}

extern "C" void kernel_launch(void* const* d_in, const int* in_sizes, int n_in,
                              void* d_out, int out_size, void* d_ws, size_t ws_size,
                              hipStream_t stream) {
    const float* x   = (const float*)d_in[0];
    const int*   ei  = (const int*)d_in[1];
    const int*   src = ei;            // edge_index[0]
    const int*   dst = ei + NE;       // edge_index[1]
    const float* Wl0 = (const float*)d_in[2];
    const float* bl0 = (const float*)d_in[3];
    const float* Wr0 = (const float*)d_in[4];
    const float* Wl1 = (const float*)d_in[5];
    const float* bl1 = (const float*)d_in[6];
    const float* Wr1 = (const float*)d_in[7];
    const float* Wl2 = (const float*)d_in[8];
    const float* bl2 = (const float*)d_in[9];
    const float* Wr2 = (const float*)d_in[10];
    float* out = (float*)d_out;

    char* ws = (char*)d_ws;
    size_t o = 0;
    u16*   h16A   = (u16*)(ws + o);   o += (size_t)NN * DD * 2;   // 6.4 MB
    u16*   h16B   = (u16*)(ws + o);   o += (size_t)NN * DD * 2;   // 6.4 MB
    u16*   bucket = (u16*)(ws + o);   o += (size_t)NN * BCAP * 2; // 6.4 MB
    int*   cursor = (int*)(ws + o);   o += (size_t)NN * 4;        // 200 KB
    int*   ovn    = (int*)(ws + o);   o += 16;                    // adjacent to cursor
    int2*  ov     = (int2*)(ws + o);  o += (size_t)OVCAP * 8;     // 32 KB

    // ---- prep: zero cursor+ovn, then fill buckets + convert x to fp16 (one launch) ----
    hipMemsetAsync(cursor, 0, (size_t)NN * 4 + 16, stream);
    k_prep<<<FG + CG, 256, 0, stream>>>(src, dst, cursor, bucket, ovn, ov, x, h16B);

    const int gg = (NN + 63) / 64;   // 782

    // layer 0: h16B(x) -> h16A (ReLU)
    k_layer<0><<<gg, 256, 0, stream>>>(h16B, cursor, bucket, ovn, ov, Wl0, bl0, Wr0, h16A, nullptr);
    // layer 1: h16A -> h16B (ReLU)
    k_layer<0><<<gg, 256, 0, stream>>>(h16A, cursor, bucket, ovn, ov, Wl1, bl1, Wr1, h16B, nullptr);
    // layer 2: h16B -> out fp32 (no ReLU)
    k_layer<1><<<gg, 256, 0, stream>>>(h16B, cursor, bucket, ovn, ov, Wl2, bl2, Wr2, nullptr, out);
}